// Round 1
// baseline (200.602 us; speedup 1.0000x reference)
//
#include <hip/hip_runtime.h>
#include <cstdint>
#include <cstddef>

// dec: [16, 3999, 512] fp32, wgt: [16, 512] fp32, out: [16, 32000] fp32
//   est[f][w] = dot(dec[f], wgt[w]);  out[8g+i] = est[g][i] + est[g-1][8+i]
//
// R7 structure: weights via SCALAR loads (SGPRs), not LDS broadcast.
//   R6 issued 512 broadcast ds_read_b128 per wave for weights (8192/CU
//   ~= 41 us at 12cyc b128 return-bus throughput) -> LDS-bound.
//   Weight addresses are wave-uniform (q=tid>>6 forced uniform via
//   readfirstlane; w,c unrolled literals), so const __restrict__ loads
//   scalarize to s_load_dwordx16; v_fmac reads the SGPR operand directly
//   (free broadcast). LDS is now only the 16 KB reduction buffer.
//   xv is double-buffered: chunk c+1 global loads issue before chunk c FMAs.

#define NBC     16
#define FRAMES  3999
#define EE      512
#define TOUT    32000
#define NGROUP  4000
#define GPB     63      // output groups per block (64 frame-slots)

__global__ __launch_bounds__(256, 4) void decoder_kernel(
    const float* __restrict__ dec,
    const float* __restrict__ wgt,
    float* __restrict__ out)
{
    __shared__ float red[4 * 16 * 64];   // 16 KB reduction buffer only

    const int tid   = threadIdx.x;
    const int bc    = blockIdx.x >> 6;   // 0..15
    const int chunk = blockIdx.x & 63;   // 0..63
    const int g0    = chunk * GPB;

    const int s = tid & 63;              // frame slot
    // K-quarter: wave-uniform; readfirstlane makes uniformity provable so
    // weight loads scalarize (s_load) instead of per-lane vector loads.
    const int q = __builtin_amdgcn_readfirstlane(tid >> 6);

    const int f = g0 - 1 + s;
    const float vmask = (f >= 0 && f < FRAMES) ? 1.0f : 0.0f;
    const int fr = min(max(f, 0), FRAMES - 1);   // clamped row for safe loads

    // this thread's contiguous K-quarter of its frame
    const float* arow  = dec + ((size_t)bc * FRAMES + fr) * EE + q * 128;
    const float* wrow  = wgt + q * 128;          // wave-uniform base

    float acc[16];
    #pragma unroll
    for (int w = 0; w < 16; ++w) acc[w] = 0.f;

    // double-buffered x: prefetch chunk c+1 while doing FMAs of chunk c
    float4 xv[2][4];
    #pragma unroll
    for (int u = 0; u < 4; ++u)
        xv[0][u] = *(const float4*)(arow + 4 * u);

    #pragma unroll
    for (int c = 0; c < 8; ++c) {
        const int cur = c & 1;           // compile-time after unroll
        if (c < 7) {
            #pragma unroll
            for (int u = 0; u < 4; ++u)
                xv[cur ^ 1][u] = *(const float4*)(arow + (c + 1) * 16 + 4 * u);
        }
        #pragma unroll
        for (int w = 0; w < 16; ++w) {
            // uniform address -> s_load_dwordx(4/16); FMA reads SGPR operand
            const float* wr = wrow + w * EE + c * 16;
            float sum = acc[w];
            #pragma unroll
            for (int u = 0; u < 4; ++u) {
                sum += xv[cur][u].x * wr[4 * u + 0];
                sum += xv[cur][u].y * wr[4 * u + 1];
                sum += xv[cur][u].z * wr[4 * u + 2];
                sum += xv[cur][u].w * wr[4 * u + 3];
            }
            acc[w] = sum;
        }
    }

    // ---- 4-way K-split reduction ----
    #pragma unroll
    for (int w = 0; w < 16; ++w)
        red[(q * 16 + w) * 64 + s] = acc[w] * vmask;
    __syncthreads();

    // ---- fused overlap-add: 504 outputs, 256 threads -> 2 iterations ----
    for (int o = tid; o < GPB * 8; o += 256) {
        const int j = o >> 3;            // group offset in block, 0..62
        const int i = o & 7;             // sample within group
        const int g = g0 + j;
        if (g < NGROUP) {
            float v = 0.f;
            #pragma unroll
            for (int qq = 0; qq < 4; ++qq)
                v += red[(qq * 16 + i) * 64 + (j + 1)]      // est[g][i]
                   + red[(qq * 16 + 8 + i) * 64 + j];       // est[g-1][8+i]
            out[(size_t)bc * TOUT + g * 8 + i] = v;
        }
    }
}

extern "C" void kernel_launch(void* const* d_in, const int* in_sizes, int n_in,
                              void* d_out, int out_size, void* d_ws, size_t ws_size,
                              hipStream_t stream) {
    const float* dec = (const float*)d_in[0];   // [8,2,3999,512] fp32
    const float* wgt = (const float*)d_in[1];   // [16,512] fp32
    float* out = (float*)d_out;                 // [8,2,32000] fp32

    decoder_kernel<<<dim3(1024), dim3(256), 0, stream>>>(dec, wgt, out);
}